// Round 3
// baseline (25.907 us; speedup 1.0000x reference)
//
#include <hip/hip_runtime.h>

#define HIDDEN 64
#define MASK_FILL -1e9f
#define EPT 8  // edges per thread

// Single fused kernel:
//   scores = relu([x[row], x[col], edge_attr] @ W1 + b1) . v + c
// where v = W2 @ Ws (folded), c = b2.Ws + bs, computed per-block in the
// prologue (W2 is 16KB -> L2-resident; cost ~300 cyc/block, amortized).
__global__ __launch_bounds__(256) void edge_score_fused(
    const float* __restrict__ x,                 // [N,1]
    const int* __restrict__ edge_index,          // [2,E] int32
    const float* __restrict__ edge_attr,         // [E,2]
    const int* __restrict__ edge_mask,           // [E] int32 (bool pushed as int)
    const float* __restrict__ W1,                // [4,64] row-major
    const float* __restrict__ b1,                // [64]
    const float* __restrict__ W2,                // [64,64] row-major
    const float* __restrict__ b2,                // [64]
    const float* __restrict__ Ws,                // [64,1]
    const float* __restrict__ bs,                // [1]
    float* __restrict__ out, int E)
{
    __shared__ float4 wPack[HIDDEN];  // (W1[0][k], W1[1][k], W1[2][k], W1[3][k])
    __shared__ float2 bv[HIDDEN];     // (b1[k], v[k])
    __shared__ float  cS;

    const int t = threadIdx.x;

    // ---------- prologue: fold weights into LDS ----------
    // v[k] = sum_j W2[k][j] * Ws[j]; thread t covers row k=t>>2, cols 16*(t&3)..+15
    {
        const float4* W2v = reinterpret_cast<const float4*>(W2 + t * 16);
        const int j0 = 16 * (t & 3);
        float p = 0.f;
#pragma unroll
        for (int i = 0; i < 4; ++i) {
            const float4 wv = W2v[i];
            const int j = j0 + 4 * i;
            p = fmaf(wv.x, Ws[j],     p);
            p = fmaf(wv.y, Ws[j + 1], p);
            p = fmaf(wv.z, Ws[j + 2], p);
            p = fmaf(wv.w, Ws[j + 3], p);
        }
        p += __shfl_xor(p, 1);
        p += __shfl_xor(p, 2);
        if ((t & 3) == 0) bv[t >> 2].y = p;
    }
    if (t < 64) {
        // stage transposed W1 (coalesced: consecutive lanes -> consecutive addr)
        wPack[t] = make_float4(W1[t], W1[64 + t], W1[128 + t], W1[192 + t]);
        bv[t].x = b1[t];
    } else if (t < 128) {
        // wave 1: c = b2 . Ws + bs (full-wave shuffle reduce)
        const int l = t - 64;
        float p = b2[l] * Ws[l];
#pragma unroll
        for (int off = 1; off < 64; off <<= 1) p += __shfl_xor(p, off);
        if (l == 0) cS = p + bs[0];
    }
    __syncthreads();

    // ---------- main: 8 edges per thread ----------
    const int tid = blockIdx.x * 256 + t;
    const int e = tid * EPT;
    if (e >= E) return;  // E % 8 == 0 -> active threads own 8 full edges

    const int4 ra = *reinterpret_cast<const int4*>(edge_index + e);
    const int4 rb = *reinterpret_cast<const int4*>(edge_index + e + 4);
    const int4 ca = *reinterpret_cast<const int4*>(edge_index + E + e);
    const int4 cb = *reinterpret_cast<const int4*>(edge_index + E + e + 4);
    const int4 ma = *reinterpret_cast<const int4*>(edge_mask + e);
    const int4 mb = *reinterpret_cast<const int4*>(edge_mask + e + 4);

    float ea0[EPT], ea1[EPT];
    {
        const float4* eav = reinterpret_cast<const float4*>(edge_attr + 2 * e);
#pragma unroll
        for (int i = 0; i < 4; ++i) {
            const float4 v = eav[i];
            ea0[2 * i] = v.x; ea1[2 * i] = v.y;
            ea0[2 * i + 1] = v.z; ea1[2 * i + 1] = v.w;
        }
    }

    // gather node features (x = 200KB, L2-resident)
    float xr[EPT], xc[EPT];
    xr[0] = x[ra.x]; xr[1] = x[ra.y]; xr[2] = x[ra.z]; xr[3] = x[ra.w];
    xr[4] = x[rb.x]; xr[5] = x[rb.y]; xr[6] = x[rb.z]; xr[7] = x[rb.w];
    xc[0] = x[ca.x]; xc[1] = x[ca.y]; xc[2] = x[ca.z]; xc[3] = x[ca.w];
    xc[4] = x[cb.x]; xc[5] = x[cb.y]; xc[6] = x[cb.z]; xc[7] = x[cb.w];

    float s[EPT];
#pragma unroll
    for (int i = 0; i < EPT; ++i) s[i] = 0.f;

#pragma unroll 16
    for (int k = 0; k < HIDDEN; ++k) {
        const float4 w = wPack[k];     // broadcast ds_read_b128
        const float2 bk = bv[k];       // broadcast ds_read_b64
#pragma unroll
        for (int i = 0; i < EPT; ++i) {
            float h = fmaf(xr[i], w.x,
                      fmaf(xc[i], w.y,
                      fmaf(ea0[i], w.z,
                      fmaf(ea1[i], w.w, bk.x))));
            s[i] = fmaf(fmaxf(h, 0.f), bk.y, s[i]);
        }
    }

    const float c = cS;
    float4 o0, o1;
    o0.x = ma.x ? (s[0] + c) : MASK_FILL;
    o0.y = ma.y ? (s[1] + c) : MASK_FILL;
    o0.z = ma.z ? (s[2] + c) : MASK_FILL;
    o0.w = ma.w ? (s[3] + c) : MASK_FILL;
    o1.x = mb.x ? (s[4] + c) : MASK_FILL;
    o1.y = mb.y ? (s[5] + c) : MASK_FILL;
    o1.z = mb.z ? (s[6] + c) : MASK_FILL;
    o1.w = mb.w ? (s[7] + c) : MASK_FILL;
    *reinterpret_cast<float4*>(out + e) = o0;
    *reinterpret_cast<float4*>(out + e + 4) = o1;
}

extern "C" void kernel_launch(void* const* d_in, const int* in_sizes, int n_in,
                              void* d_out, int out_size, void* d_ws, size_t ws_size,
                              hipStream_t stream) {
    const float* x          = (const float*)d_in[0];
    const int*   edge_index = (const int*)d_in[1];   // int64 request -> int32 (x64 off)
    const float* edge_attr  = (const float*)d_in[2];
    const int*   edge_mask  = (const int*)d_in[3];   // bool pushed as int32
    const float* W1 = (const float*)d_in[4];
    const float* b1 = (const float*)d_in[5];
    const float* W2 = (const float*)d_in[6];
    const float* b2 = (const float*)d_in[7];
    const float* Ws = (const float*)d_in[8];
    const float* bs = (const float*)d_in[9];
    float* out = (float*)d_out;

    const int E = out_size;  // 1,000,000
    const int threads = 256;
    const int work = (E + EPT - 1) / EPT;
    const int blocks = (work + threads - 1) / threads;
    edge_score_fused<<<blocks, threads, 0, stream>>>(
        x, edge_index, edge_attr, edge_mask, W1, b1, W2, b2, Ws, bs, out, E);
}

// Round 4
// 21.310 us; speedup vs baseline: 1.2157x; 1.2157x over previous
//
#include <hip/hip_runtime.h>

#define HIDDEN 64
#define MASK_FILL -1e9f
#define EPT 4  // edges per thread

// Single fused kernel:
//   scores = relu([x[row], x[col], edge_attr] @ W1 + b1) . v + c
// where v = W2 @ Ws (folded), c = b2.Ws + bs, computed per-block in the
// prologue (W2 is 16KB -> L2-resident, coalesced float4 reads).
__global__ __launch_bounds__(256) void edge_score_fused(
    const float* __restrict__ x,                 // [N,1]
    const int* __restrict__ edge_index,          // [2,E] int32
    const float* __restrict__ edge_attr,         // [E,2]
    const int* __restrict__ edge_mask,           // [E] int32 (bool pushed as int)
    const float* __restrict__ W1,                // [4,64] row-major
    const float* __restrict__ b1,                // [64]
    const float* __restrict__ W2,                // [64,64] row-major
    const float* __restrict__ b2,                // [64]
    const float* __restrict__ Ws,                // [64,1]
    const float* __restrict__ bs,                // [1]
    float* __restrict__ out, int E)
{
    __shared__ float4 wPack[HIDDEN];  // (W1[0][k], W1[1][k], W1[2][k], W1[3][k])
    __shared__ float2 bv[HIDDEN];     // (b1[k], v[k])
    __shared__ float  cS;

    const int t = threadIdx.x;

    // ---------- prologue: fold weights into LDS ----------
    // v[k] = sum_j W2[k][j] * Ws[j]; thread t covers row k=t>>2, cols 16*(t&3)..+15
    {
        const float4* W2v = reinterpret_cast<const float4*>(W2 + t * 16);
        const int j0 = 16 * (t & 3);
        float p = 0.f;
#pragma unroll
        for (int i = 0; i < 4; ++i) {
            const float4 wv = W2v[i];
            const int j = j0 + 4 * i;
            p = fmaf(wv.x, Ws[j],     p);
            p = fmaf(wv.y, Ws[j + 1], p);
            p = fmaf(wv.z, Ws[j + 2], p);
            p = fmaf(wv.w, Ws[j + 3], p);
        }
        p += __shfl_xor(p, 1);
        p += __shfl_xor(p, 2);
        if ((t & 3) == 0) bv[t >> 2].y = p;
    }
    if (t < 64) {
        // stage transposed W1 (coalesced: consecutive lanes -> consecutive addr)
        wPack[t] = make_float4(W1[t], W1[64 + t], W1[128 + t], W1[192 + t]);
        bv[t].x = b1[t];
    } else if (t < 128) {
        // wave 1: c = b2 . Ws + bs (full-wave shuffle reduce)
        const int l = t - 64;
        float p = b2[l] * Ws[l];
#pragma unroll
        for (int off = 1; off < 64; off <<= 1) p += __shfl_xor(p, off);
        if (l == 0) cS = p + bs[0];
    }
    __syncthreads();

    // ---------- main: 4 edges per thread ----------
    const int tid = blockIdx.x * 256 + t;
    const int e = tid * EPT;
    if (e >= E) return;  // E % 4 == 0 -> active threads own 4 full edges

    const int4 rows = *reinterpret_cast<const int4*>(edge_index + e);
    const int4 cols = *reinterpret_cast<const int4*>(edge_index + E + e);
    const int4 mk   = *reinterpret_cast<const int4*>(edge_mask + e);
    const float4 eaA = *reinterpret_cast<const float4*>(edge_attr + 2 * e);
    const float4 eaB = *reinterpret_cast<const float4*>(edge_attr + 2 * e + 4);

    // gather node features (x = 200KB, L2-resident)
    const float xr0 = x[rows.x], xr1 = x[rows.y], xr2 = x[rows.z], xr3 = x[rows.w];
    const float xc0 = x[cols.x], xc1 = x[cols.y], xc2 = x[cols.z], xc3 = x[cols.w];

    const float c = cS;
    float s0 = c, s1 = c, s2 = c, s3 = c;

#pragma unroll 4
    for (int k = 0; k < HIDDEN; ++k) {
        const float4 w  = wPack[k];    // broadcast ds_read_b128
        const float2 bk = bv[k];       // broadcast ds_read_b64

        float h0 = fmaf(xr0, w.x, fmaf(xc0, w.y, fmaf(eaA.x, w.z, fmaf(eaA.y, w.w, bk.x))));
        float h1 = fmaf(xr1, w.x, fmaf(xc1, w.y, fmaf(eaA.z, w.z, fmaf(eaA.w, w.w, bk.x))));
        float h2 = fmaf(xr2, w.x, fmaf(xc2, w.y, fmaf(eaB.x, w.z, fmaf(eaB.y, w.w, bk.x))));
        float h3 = fmaf(xr3, w.x, fmaf(xc3, w.y, fmaf(eaB.z, w.z, fmaf(eaB.w, w.w, bk.x))));
        s0 = fmaf(fmaxf(h0, 0.f), bk.y, s0);
        s1 = fmaf(fmaxf(h1, 0.f), bk.y, s1);
        s2 = fmaf(fmaxf(h2, 0.f), bk.y, s2);
        s3 = fmaf(fmaxf(h3, 0.f), bk.y, s3);
    }

    float4 res;
    res.x = mk.x ? s0 : MASK_FILL;
    res.y = mk.y ? s1 : MASK_FILL;
    res.z = mk.z ? s2 : MASK_FILL;
    res.w = mk.w ? s3 : MASK_FILL;
    *reinterpret_cast<float4*>(out + e) = res;
}

extern "C" void kernel_launch(void* const* d_in, const int* in_sizes, int n_in,
                              void* d_out, int out_size, void* d_ws, size_t ws_size,
                              hipStream_t stream) {
    const float* x          = (const float*)d_in[0];
    const int*   edge_index = (const int*)d_in[1];   // int64 request -> int32 (x64 off)
    const float* edge_attr  = (const float*)d_in[2];
    const int*   edge_mask  = (const int*)d_in[3];   // bool pushed as int32
    const float* W1 = (const float*)d_in[4];
    const float* b1 = (const float*)d_in[5];
    const float* W2 = (const float*)d_in[6];
    const float* b2 = (const float*)d_in[7];
    const float* Ws = (const float*)d_in[8];
    const float* bs = (const float*)d_in[9];
    float* out = (float*)d_out;

    const int E = out_size;  // 1,000,000
    const int threads = 256;
    const int work = (E + EPT - 1) / EPT;
    const int blocks = (work + threads - 1) / threads;
    edge_score_fused<<<blocks, threads, 0, stream>>>(
        x, edge_index, edge_attr, edge_mask, W1, b1, W2, b2, Ws, bs, out, E);
}

// Round 6
// 19.602 us; speedup vs baseline: 1.3217x; 1.0871x over previous
//
#include <hip/hip_runtime.h>

typedef float f2 __attribute__((ext_vector_type(2)));
typedef float f4 __attribute__((ext_vector_type(4)));
typedef int   i4 __attribute__((ext_vector_type(4)));

#define HIDDEN 64
#define MASK_FILL -1e9f
#define EPT 4  // edges per thread

// scores = relu([x[row], x[col], edge_attr] @ W1 + b1) . v + c
// v = W2 @ Ws, c = b2.Ws + bs  (folded per-block in prologue)
// k-loop processed in PAIRS with float2 -> v_pk_fma_f32 (VOP3P packed fp32).
__global__ __launch_bounds__(256) void edge_score_fused(
    const float* __restrict__ x,                 // [N,1]
    const int* __restrict__ edge_index,          // [2,E] int32
    const float* __restrict__ edge_attr,         // [E,2]
    const int* __restrict__ edge_mask,           // [E] int32
    const float* __restrict__ W1,                // [4,64]
    const float* __restrict__ b1,                // [64]
    const float* __restrict__ W2,                // [64,64]
    const float* __restrict__ b2,                // [64]
    const float* __restrict__ Ws,                // [64,1]
    const float* __restrict__ bs,                // [1]
    float* __restrict__ out, int E)
{
    // per k-pair k2: wA=(w0_lo,w0_hi,w1_lo,w1_hi) wB=(w2_lo,w2_hi,w3_lo,w3_hi)
    //               wC=(b_lo,b_hi,v_lo,v_hi)
    __shared__ f4 wA[32], wB[32], wC[32];
    __shared__ float cS;

    const int t = threadIdx.x;

    // ---------- prologue ----------
    // v[k] = W2[k]·Ws : thread t -> row k=t>>2, 16 cols starting 16*(t&3)
    {
        const f4* W2v = reinterpret_cast<const f4*>(W2 + t * 16);
        const int j0 = 16 * (t & 3);
        float p = 0.f;
#pragma unroll
        for (int i = 0; i < 4; ++i) {
            const f4 wv = W2v[i];
            const int j = j0 + 4 * i;
            p = fmaf(wv.x, Ws[j], p);
            p = fmaf(wv.y, Ws[j + 1], p);
            p = fmaf(wv.z, Ws[j + 2], p);
            p = fmaf(wv.w, Ws[j + 3], p);
        }
        p += __shfl_xor(p, 1);
        p += __shfl_xor(p, 2);
        if ((t & 3) == 0) {
            const int k = t >> 2;
            reinterpret_cast<float*>(&wC[k >> 1])[2 + (k & 1)] = p;  // v
        }
    }
    if (t < 32) {
        wA[t] = (f4){W1[2 * t], W1[2 * t + 1], W1[64 + 2 * t], W1[64 + 2 * t + 1]};
        wB[t] = (f4){W1[128 + 2 * t], W1[128 + 2 * t + 1], W1[192 + 2 * t], W1[192 + 2 * t + 1]};
    } else if (t >= 64 && t < 128) {
        // wave 1: c = b2·Ws + bs
        const int l = t - 64;
        float p = b2[l] * Ws[l];
#pragma unroll
        for (int off = 1; off < 64; off <<= 1) p += __shfl_xor(p, off);
        if (l == 0) cS = p + bs[0];
    } else if (t >= 192) {
        const int k = t - 192;  // b1
        reinterpret_cast<float*>(&wC[k >> 1])[k & 1] = b1[k];
    }
    __syncthreads();

    // ---------- main: 4 edges / thread ----------
    const int tid = blockIdx.x * 256 + t;
    const int e = tid * EPT;
    if (e >= E) return;  // E % 4 == 0

    const i4 rows = __builtin_nontemporal_load(reinterpret_cast<const i4*>(edge_index + e));
    const i4 cols = __builtin_nontemporal_load(reinterpret_cast<const i4*>(edge_index + E + e));
    const i4 mk   = __builtin_nontemporal_load(reinterpret_cast<const i4*>(edge_mask + e));
    const f4 eaA  = __builtin_nontemporal_load(reinterpret_cast<const f4*>(edge_attr + 2 * e));
    const f4 eaB  = __builtin_nontemporal_load(reinterpret_cast<const f4*>(edge_attr + 2 * e + 4));

    // gathers (x = 200KB, L2-resident; nt on streams keeps it cached)
    const f2 xr0 = {x[rows.x], x[rows.x]}, xr1 = {x[rows.y], x[rows.y]},
             xr2 = {x[rows.z], x[rows.z]}, xr3 = {x[rows.w], x[rows.w]};
    const f2 xc0 = {x[cols.x], x[cols.x]}, xc1 = {x[cols.y], x[cols.y]},
             xc2 = {x[cols.z], x[cols.z]}, xc3 = {x[cols.w], x[cols.w]};
    const f2 e00 = {eaA.x, eaA.x}, e10 = {eaA.y, eaA.y};
    const f2 e01 = {eaA.z, eaA.z}, e11 = {eaA.w, eaA.w};
    const f2 e02 = {eaB.x, eaB.x}, e12 = {eaB.y, eaB.y};
    const f2 e03 = {eaB.z, eaB.z}, e13 = {eaB.w, eaB.w};

    const float c = cS;
    const f2 z2 = {0.f, 0.f};
    f2 a0 = {c, 0.f}, a1 = {c, 0.f}, a2 = {c, 0.f}, a3 = {c, 0.f};

#pragma unroll 4
    for (int k2 = 0; k2 < 32; ++k2) {
        const f4 A = wA[k2];   // ds_read_b128 broadcast
        const f4 B = wB[k2];
        const f4 C = wC[k2];
        const f2 w0 = {A.x, A.y}, w1 = {A.z, A.w};
        const f2 w2 = {B.x, B.y}, w3 = {B.z, B.w};
        const f2 bb = {C.x, C.y}, vv = {C.z, C.w};

        f2 h0 = __builtin_elementwise_fma(xr0, w0, __builtin_elementwise_fma(xc0, w1,
                __builtin_elementwise_fma(e00, w2, __builtin_elementwise_fma(e10, w3, bb))));
        f2 h1 = __builtin_elementwise_fma(xr1, w0, __builtin_elementwise_fma(xc1, w1,
                __builtin_elementwise_fma(e01, w2, __builtin_elementwise_fma(e11, w3, bb))));
        f2 h2 = __builtin_elementwise_fma(xr2, w0, __builtin_elementwise_fma(xc2, w1,
                __builtin_elementwise_fma(e02, w2, __builtin_elementwise_fma(e12, w3, bb))));
        f2 h3 = __builtin_elementwise_fma(xr3, w0, __builtin_elementwise_fma(xc3, w1,
                __builtin_elementwise_fma(e03, w2, __builtin_elementwise_fma(e13, w3, bb))));
        a0 = __builtin_elementwise_fma(__builtin_elementwise_max(h0, z2), vv, a0);
        a1 = __builtin_elementwise_fma(__builtin_elementwise_max(h1, z2), vv, a1);
        a2 = __builtin_elementwise_fma(__builtin_elementwise_max(h2, z2), vv, a2);
        a3 = __builtin_elementwise_fma(__builtin_elementwise_max(h3, z2), vv, a3);
    }

    f4 res;
    res.x = mk.x ? (a0.x + a0.y) : MASK_FILL;
    res.y = mk.y ? (a1.x + a1.y) : MASK_FILL;
    res.z = mk.z ? (a2.x + a2.y) : MASK_FILL;
    res.w = mk.w ? (a3.x + a3.y) : MASK_FILL;
    __builtin_nontemporal_store(res, reinterpret_cast<f4*>(out + e));
}

extern "C" void kernel_launch(void* const* d_in, const int* in_sizes, int n_in,
                              void* d_out, int out_size, void* d_ws, size_t ws_size,
                              hipStream_t stream) {
    const float* x          = (const float*)d_in[0];
    const int*   edge_index = (const int*)d_in[1];
    const float* edge_attr  = (const float*)d_in[2];
    const int*   edge_mask  = (const int*)d_in[3];
    const float* W1 = (const float*)d_in[4];
    const float* b1 = (const float*)d_in[5];
    const float* W2 = (const float*)d_in[6];
    const float* b2 = (const float*)d_in[7];
    const float* Ws = (const float*)d_in[8];
    const float* bs = (const float*)d_in[9];
    float* out = (float*)d_out;

    const int E = out_size;  // 1,000,000
    const int threads = 256;
    const int work = (E + EPT - 1) / EPT;
    const int blocks = (work + threads - 1) / threads;
    edge_score_fused<<<blocks, threads, 0, stream>>>(
        x, edge_index, edge_attr, edge_mask, W1, b1, W2, b2, Ws, bs, out, E);
}